// Round 6
// baseline (1099.783 us; speedup 1.0000x reference)
//
#include <hip/hip_runtime.h>
#include <hip/hip_bf16.h>
#include <math.h>

// Problem: b=4, n=4096, d=64.
// d_out (fp32 concat): [loss(1)] [pred_attn 4*4096*4096] [true_attn 4*4096*4096]
//
// ws layout (ushort/bf16 unless noted), element offsets:
//   qbh 0        qbl 1048576   kbh 2097152   kbl 3145728     (each 4*4096*64)
//   qfh 4194304  qfl 6291456   kfh 8388608   kfl 10485760    (each 4*4096*128)
//   then floats at ushort offset 12582912:
//     mt[16384] ist[16384] mp[16384] isp[16384] partials[4096]
//
// R6 changes vs R3/R5 (828.8 us measured):
//  - __expf/__logf in stats + scores_write epilogues (libcall logf ~25 VALU,
//    expf ~10; epilogue was ~80 us of pure VALU). proj unchanged.
//  - nontemporal stores for the 537 MB prob streams (stop evicting the 24 MB
//    ws from L2 between staging rounds).
//  - NO layout/sync changes: MFMA, staging, swizzles identical to R5.

#define B 4
#define N 4096
#define D 64
#define NROWS (B * N)
#define ATTN_ELEMS ((size_t)B * N * N)
#define FSTAT_BASE 12582912  // ushort offset of float stats area

typedef __attribute__((ext_vector_type(8))) short short8;   // 8 bf16 = 4 VGPRs
typedef __attribute__((ext_vector_type(4))) float float4v;  // MFMA C/D

typedef unsigned short ushort_t;

__device__ __forceinline__ float fast_exp(float x) { return __expf(x); }
__device__ __forceinline__ float fast_log(float x) { return __logf(x); }

__device__ __forceinline__ void split_bf16(float x, ushort_t& hi, ushort_t& lo) {
  __hip_bfloat16 h = __float2bfloat16(x);
  float r = x - __bfloat162float(h);
  __hip_bfloat16 l = __float2bfloat16(r);
  hi = *(ushort_t*)&h;
  lo = *(ushort_t*)&l;
}

__device__ __forceinline__ void gload_lds16(const ushort_t* g, ushort_t* l) {
  __builtin_amdgcn_global_load_lds(
      (const __attribute__((address_space(1))) unsigned int*)g,
      (__attribute__((address_space(3))) unsigned int*)l, 16, 0, 0);
}

__device__ __forceinline__ float block_reduce(float v, bool is_max, float* red) {
#pragma unroll
  for (int o = 32; o > 0; o >>= 1) {
    float other = __shfl_down(v, o);
    v = is_max ? fmaxf(v, other) : (v + other);
  }
  int w = threadIdx.x >> 6;
  __syncthreads();
  if ((threadIdx.x & 63) == 0) red[w] = v;
  __syncthreads();
  return is_max ? fmaxf(fmaxf(red[0], red[1]), fmaxf(red[2], red[3]))
                : (red[0] + red[1] + red[2] + red[3]);
}

// ---------------------------------------------------------------------------
// Kernel 1: projections + feature maps + split-bf16 (unchanged from R2).
// ---------------------------------------------------------------------------
#define PR 32

__global__ __launch_bounds__(256, 2) void proj_kernel(
    const float* __restrict__ hidden,
    const float* __restrict__ Wq_mlp, const float* __restrict__ bq_mlp,
    const float* __restrict__ Wk_mlp, const float* __restrict__ bk_mlp,
    const float* __restrict__ Wq_base, const float* __restrict__ Wk_base,
    ushort_t* __restrict__ ws) {
  ushort_t* qbh = ws;
  ushort_t* qbl = ws + 1048576;
  ushort_t* kbh = ws + 2097152;
  ushort_t* kbl = ws + 3145728;
  ushort_t* qfh = ws + 4194304;
  ushort_t* qfl = ws + 6291456;
  ushort_t* kfh = ws + 8388608;
  ushort_t* kfl = ws + 10485760;

  __shared__ float wt[4][64 * 64];  // 64 KB: [mat][d*64 + (e ^ (d&31))]
  __shared__ float hs[PR][64];      // 8 KB

  const int tid = threadIdx.x;
  const int r0 = blockIdx.x * PR;

  {
    const float* Wm[4] = {Wq_base, Wk_base, Wq_mlp, Wk_mlp};
#pragma unroll
    for (int m = 0; m < 4; ++m)
      for (int idx = tid; idx < 4096; idx += 256) {
        const int e = idx >> 6, d = idx & 63;
        wt[m][d * 64 + (e ^ (d & 31))] = Wm[m][idx];
      }
  }
  for (int idx = tid; idx < PR * 64; idx += 256)
    hs[idx >> 6][idx & 63] = hidden[(size_t)r0 * 64 + idx];
  __syncthreads();

  const int e = tid & 63;
  const int g0 = (tid >> 6) * (PR / 4);  // 8 rows per thread

  float aqb[PR / 4], akb[PR / 4], zq[PR / 4], zk[PR / 4];
  const float bq = bq_mlp[e], bk = bk_mlp[e];
#pragma unroll
  for (int g = 0; g < PR / 4; ++g) {
    aqb[g] = 0.f; akb[g] = 0.f; zq[g] = bq; zk[g] = bk;
  }

#pragma unroll 8
  for (int d = 0; d < 64; ++d) {
    const int wi = d * 64 + (e ^ (d & 31));
    const float w0 = wt[0][wi];
    const float w1 = wt[1][wi];
    const float w2 = wt[2][wi];
    const float w3 = wt[3][wi];
#pragma unroll
    for (int g = 0; g < PR / 4; ++g) {
      const float hd = hs[g0 + g][d];
      aqb[g] += hd * w0;
      akb[g] += hd * w1;
      zq[g] += hd * w2;
      zk[g] += hd * w3;
    }
  }

#pragma unroll
  for (int g = 0; g < PR / 4; ++g) {
    const int row = r0 + g0 + g;
    const size_t rb = (size_t)row * D + e;       // base rows, stride 64
    const size_t rf = (size_t)row * 2 * D + e;   // feature rows, stride 128
    ushort_t hi, lo;
    split_bf16(aqb[g], hi, lo);        qbh[rb] = hi; qbl[rb] = lo;
    split_bf16(akb[g], hi, lo);        kbh[rb] = hi; kbl[rb] = lo;
    split_bf16(expf(zq[g]), hi, lo);   qfh[rf] = hi; qfl[rf] = lo;
    split_bf16(expf(-zq[g]), hi, lo);  qfh[rf + D] = hi; qfl[rf + D] = lo;
    split_bf16(expf(zk[g]), hi, lo);   kfh[rf] = hi; kfl[rf] = lo;
    split_bf16(expf(-zk[g]), hi, lo);  kfh[rf + D] = hi; kfl[rf + D] = lo;
  }
}

// ---------------------------------------------------------------------------
// Kernel 2: row softmax stats (MT, 1/ST, MP, 1/SP) via recompute, no score
// write. Structure unchanged from R5; expf -> __expf only.
// ---------------------------------------------------------------------------
__global__ __launch_bounds__(256) void stats_kernel(
    const ushort_t* __restrict__ ws, float* __restrict__ fst) {
  const ushort_t* qbh = ws;
  const ushort_t* qbl = ws + 1048576;
  const ushort_t* kbh = ws + 2097152;
  const ushort_t* kbl = ws + 3145728;
  const ushort_t* qfh = ws + 4194304;
  const ushort_t* qfl = ws + 6291456;
  const ushort_t* kfh = ws + 8388608;
  const ushort_t* kfl = ws + 10485760;

  float* mt_ = fst;
  float* ist_ = fst + 16384;
  float* mp_ = fst + 32768;
  float* isp_ = fst + 49152;

  __shared__ ushort_t sbh[128 * 64];    // 16 KB
  __shared__ ushort_t sbl[128 * 64];    // 16 KB
  __shared__ ushort_t sfh[128 * 128];   // 32 KB
  __shared__ ushort_t sfl[128 * 128];   // 32 KB

  const int bid0 = blockIdx.x;                     // 0..255
  const int bid = (bid0 & 7) * 32 + (bid0 >> 3);   // XCD-chunked, bijective
  const int bt = bid >> 6;                         // batch
  const int m0 = (bid & 63) * 64;                  // 64-row strip
  const int tid = threadIdx.x;
  const int w = tid >> 6;                          // wave: rows m0+w*16..+16
  const int lane = tid & 63;
  const int fr = lane & 15;
  const int quad = lane >> 4;
  const size_t rowb = (size_t)bt * N;

  // A fragments: row = fr (within wave strip), k-slice = quad*8 + kk*32
  const size_t ar = rowb + m0 + w * 16 + fr;
  short8 ath[2], atl[2], aph[4], apl[4];
#pragma unroll
  for (int kk = 0; kk < 2; ++kk) {
    ath[kk] = *(const short8*)&qbh[ar * 64 + kk * 32 + quad * 8];
    atl[kk] = *(const short8*)&qbl[ar * 64 + kk * 32 + quad * 8];
  }
#pragma unroll
  for (int kk = 0; kk < 4; ++kk) {
    aph[kk] = *(const short8*)&qfh[ar * 128 + kk * 32 + quad * 8];
    apl[kk] = *(const short8*)&qfl[ar * 128 + kk * 32 + quad * 8];
  }

  const int sr8 = lane >> 3, su8 = (lane & 7) ^ (lane >> 3);  // kb staging
  const int r4 = lane >> 4, u16 = lane & 15;                  // kf staging

  float m_t[4], s_t[4], m_p[4], s_p[4];
#pragma unroll
  for (int r = 0; r < 4; ++r) {
    m_t[r] = -INFINITY; s_t[r] = 0.f;
    m_p[r] = -INFINITY; s_p[r] = 0.f;
  }

  for (int c = 0; c < 32; ++c) {
    const int n0 = c * 128;
    __syncthreads();
    // stage kb: 16 groups of 8 rows x 64 ushort; wave w takes g = j*4+w
#pragma unroll
    for (int j = 0; j < 4; ++j) {
      const int g = j * 4 + w;
      const size_t grow = rowb + n0 + g * 8 + sr8;
      gload_lds16(kbh + grow * 64 + su8 * 8, &sbh[g * 512]);
      gload_lds16(kbl + grow * 64 + su8 * 8, &sbl[g * 512]);
    }
    // stage kf: 32 groups of 4 rows x 128 ushort
#pragma unroll
    for (int j = 0; j < 8; ++j) {
      const int g = j * 4 + w;
      const int su = u16 ^ ((g & 1) * 4 + r4);   // = u ^ (row&7)
      const size_t grow = rowb + n0 + g * 4 + r4;
      gload_lds16(kfh + grow * 128 + su * 8, &sfh[g * 512]);
      gload_lds16(kfl + grow * 128 + su * 8, &sfl[g * 512]);
    }
    __syncthreads();

    // ---- true scores: K=64 ----
    float4v acct[8];
#pragma unroll
    for (int tn = 0; tn < 8; ++tn) acct[tn] = (float4v)0.f;
#pragma unroll
    for (int tn = 0; tn < 8; ++tn) {
      const int brow = tn * 16 + fr;
#pragma unroll
      for (int kk = 0; kk < 2; ++kk) {
        const int u = ((kk * 4 + quad) ^ (fr & 7)) * 8;
        short8 bh = *(const short8*)&sbh[brow * 64 + u];
        short8 bl = *(const short8*)&sbl[brow * 64 + u];
        acct[tn] = __builtin_amdgcn_mfma_f32_16x16x32_bf16(ath[kk], bh, acct[tn], 0, 0, 0);
        acct[tn] = __builtin_amdgcn_mfma_f32_16x16x32_bf16(ath[kk], bl, acct[tn], 0, 0, 0);
        acct[tn] = __builtin_amdgcn_mfma_f32_16x16x32_bf16(atl[kk], bh, acct[tn], 0, 0, 0);
      }
    }
#pragma unroll
    for (int r = 0; r < 4; ++r) {
      float vm = m_t[r];
      float v[8];
#pragma unroll
      for (int tn = 0; tn < 8; ++tn) { v[tn] = acct[tn][r] * 0.125f; vm = fmaxf(vm, v[tn]); }
      float ss = s_t[r] * fast_exp(m_t[r] - vm);
#pragma unroll
      for (int tn = 0; tn < 8; ++tn) ss += fast_exp(v[tn] - vm);
      m_t[r] = vm; s_t[r] = ss;
    }

    // ---- pred scores: K=128 ----
    float4v accp[8];
#pragma unroll
    for (int tn = 0; tn < 8; ++tn) accp[tn] = (float4v)0.f;
#pragma unroll
    for (int tn = 0; tn < 8; ++tn) {
      const int brow = tn * 16 + fr;
#pragma unroll
      for (int kk = 0; kk < 4; ++kk) {
        const int u = ((kk * 4 + quad) ^ (fr & 7)) * 8;
        short8 bh = *(const short8*)&sfh[brow * 128 + u];
        short8 bl = *(const short8*)&sfl[brow * 128 + u];
        accp[tn] = __builtin_amdgcn_mfma_f32_16x16x32_bf16(aph[kk], bh, accp[tn], 0, 0, 0);
        accp[tn] = __builtin_amdgcn_mfma_f32_16x16x32_bf16(aph[kk], bl, accp[tn], 0, 0, 0);
        accp[tn] = __builtin_amdgcn_mfma_f32_16x16x32_bf16(apl[kk], bh, accp[tn], 0, 0, 0);
      }
    }
#pragma unroll
    for (int r = 0; r < 4; ++r) {
      float vm = m_p[r];
      float v[8];
#pragma unroll
      for (int tn = 0; tn < 8; ++tn) { v[tn] = accp[tn][r]; vm = fmaxf(vm, v[tn]); }
      float ss = s_p[r] * fast_exp(m_p[r] - vm);
#pragma unroll
      for (int tn = 0; tn < 8; ++tn) ss += fast_exp(v[tn] - vm);
      m_p[r] = vm; s_p[r] = ss;
    }
  }

  // combine across the 16 fr lanes (masks 1,2,4,8 stay within quad group)
#pragma unroll
  for (int r = 0; r < 4; ++r) {
    {
      float m = m_t[r], s = s_t[r];
#pragma unroll
      for (int o = 1; o < 16; o <<= 1) {
        float m2 = __shfl_xor(m, o);
        float s2 = __shfl_xor(s, o);
        float M = fmaxf(m, m2);
        s = s * fast_exp(m - M) + s2 * fast_exp(m2 - M);
        m = M;
      }
      if (fr == 0) {
        const size_t row = rowb + m0 + w * 16 + quad * 4 + r;
        mt_[row] = m; ist_[row] = 1.f / s;
      }
    }
    {
      float m = m_p[r], s = s_p[r];
#pragma unroll
      for (int o = 1; o < 16; o <<= 1) {
        float m2 = __shfl_xor(m, o);
        float s2 = __shfl_xor(s, o);
        float M = fmaxf(m, m2);
        s = s * fast_exp(m - M) + s2 * fast_exp(m2 - M);
        m = M;
      }
      if (fr == 0) {
        const size_t row = rowb + m0 + w * 16 + quad * 4 + r;
        mp_[row] = m; isp_[row] = 1.f / s;
      }
    }
  }
}

// ---------------------------------------------------------------------------
// Kernel 3: scores -> NORMALIZED probabilities + loss partials.
// Structure unchanged from R5; epilogue uses __expf/__logf + nt stores.
// ---------------------------------------------------------------------------
__global__ __launch_bounds__(256, 2) void scores_write_kernel(
    const ushort_t* __restrict__ ws, float* __restrict__ out,
    float* __restrict__ fst) {
  const ushort_t* qbh = ws;
  const ushort_t* qbl = ws + 1048576;
  const ushort_t* kbh = ws + 2097152;
  const ushort_t* kbl = ws + 3145728;
  const ushort_t* qfh = ws + 4194304;
  const ushort_t* qfl = ws + 6291456;
  const ushort_t* kfh = ws + 8388608;
  const ushort_t* kfl = ws + 10485760;

  const float* mt_ = fst;
  const float* ist_ = fst + 16384;
  const float* mp_ = fst + 32768;
  const float* isp_ = fst + 49152;
  float* partials = fst + 65536;

  __shared__ ushort_t sAh[128 * 64];
  __shared__ ushort_t sAl[128 * 64];
  __shared__ ushort_t sBh[128 * 64];
  __shared__ ushort_t sBl[128 * 64];
  __shared__ float red[4];

  const int bt = blockIdx.z;
  const int f = blockIdx.x + 32 * blockIdx.y;     // 0..1023, %8 tracks XCD
  const int nf = (f & 7) * 128 + (f >> 3);        // bijective chunked swizzle
  const int m0 = (nf >> 5) * 128;
  const int n0 = (nf & 31) * 128;

  const int tid = threadIdx.x;
  const int lane = tid & 63;
  const int w = tid >> 6;
  const int qr = w >> 1, qc = w & 1;     // quadrant row/col (64 each)
  const int fr = lane & 15;              // fragment row within 16
  const int quad = lane >> 4;            // 0..3

  const int srow = lane >> 3;                 // r&7 of this lane's stage row
  const int sunit = (lane & 7) ^ srow;        // pre-swizzled source unit

  const size_t rowb = (size_t)bt * N;
  float* pred = out + 1;
  float* tru  = out + 1 + ATTN_ELEMS;

  float4v tsave[4][4];   // normalized true tile, phase0 -> phase1 loss
  float lloss = 0.f;

#pragma unroll
  for (int phase = 0; phase < 2; ++phase) {
    const ushort_t* Ah = phase ? qfh : qbh;
    const ushort_t* Al = phase ? qfl : qbl;
    const ushort_t* Bh = phase ? kfh : kbh;
    const ushort_t* Bl = phase ? kfl : kbl;
    const int Krow = phase ? 128 : 64;
    const int nchunk = Krow / 64;
    const float scale = phase ? 1.0f : 0.125f;
    float* dst = phase ? pred : tru;

    float4v acc[4][4];
#pragma unroll
    for (int i = 0; i < 4; ++i)
#pragma unroll
      for (int j = 0; j < 4; ++j) acc[i][j] = (float4v)0.f;

    for (int ck = 0; ck < nchunk; ++ck) {
      const int kc = ck * 64;
      __syncthreads();  // previous chunk's fragment reads done
#pragma unroll
      for (int j = 0; j < 4; ++j) {
        const int chunk = j * 4 + w;
        const int r = chunk * 8 + srow;
        const int loff = chunk * 512;  // ushort offset of 1 KB chunk
        const size_t gA = (size_t)(rowb + m0 + r) * Krow + kc + sunit * 8;
        const size_t gB = (size_t)(rowb + n0 + r) * Krow + kc + sunit * 8;
        gload_lds16(Ah + gA, &sAh[loff]);
        gload_lds16(Al + gA, &sAl[loff]);
        gload_lds16(Bh + gB, &sBh[loff]);
        gload_lds16(Bl + gB, &sBl[loff]);
      }
      __syncthreads();  // vmcnt(0) drain emitted by compiler before barrier

#pragma unroll
      for (int kk = 0; kk < 2; ++kk) {
        short8 ah[4], al[4], bh[4], bl[4];
        const int u8 = ((kk * 4 + quad) ^ (fr & 7)) * 8;  // swizzled unit
#pragma unroll
        for (int t = 0; t < 4; ++t) {
          const int offA = (qr * 64 + t * 16 + fr) * 64 + u8;
          const int offB = (qc * 64 + t * 16 + fr) * 64 + u8;
          ah[t] = *(const short8*)&sAh[offA];
          al[t] = *(const short8*)&sAl[offA];
          bh[t] = *(const short8*)&sBh[offB];
          bl[t] = *(const short8*)&sBl[offB];
        }
#pragma unroll
        for (int tm = 0; tm < 4; ++tm)
#pragma unroll
          for (int tn = 0; tn < 4; ++tn) {
            acc[tm][tn] = __builtin_amdgcn_mfma_f32_16x16x32_bf16(
                ah[tm], bh[tn], acc[tm][tn], 0, 0, 0);
            acc[tm][tn] = __builtin_amdgcn_mfma_f32_16x16x32_bf16(
                ah[tm], bl[tn], acc[tm][tn], 0, 0, 0);
            acc[tm][tn] = __builtin_amdgcn_mfma_f32_16x16x32_bf16(
                al[tm], bh[tn], acc[tm][tn], 0, 0, 0);
          }
      }
    }

    // epilogue: normalize with precomputed row stats, nt-write, track loss
#pragma unroll
    for (int tm = 0; tm < 4; ++tm) {
      const int rbase = m0 + qr * 64 + tm * 16 + quad * 4;
      float mrow[4], isrow[4];
#pragma unroll
      for (int reg = 0; reg < 4; ++reg) {
        const size_t gr = rowb + rbase + reg;
        mrow[reg]  = phase ? mp_[gr]  : mt_[gr];
        isrow[reg] = phase ? isp_[gr] : ist_[gr];
      }
#pragma unroll
      for (int tn = 0; tn < 4; ++tn) {
        const int c = n0 + qc * 64 + tn * 16 + fr;
        float4v v = acc[tm][tn];
        float4v pv;
#pragma unroll
        for (int reg = 0; reg < 4; ++reg)
          pv[reg] = fast_exp(v[reg] * scale - mrow[reg]) * isrow[reg];
#pragma unroll
        for (int reg = 0; reg < 4; ++reg)
          __builtin_nontemporal_store(pv[reg],
                                      &dst[(rowb + rbase + reg) * N + c]);
        if (phase == 0) {
          tsave[tm][tn] = pv;
        } else {
#pragma unroll
          for (int reg = 0; reg < 4; ++reg)
            lloss -= tsave[tm][tn][reg] * fast_log(pv[reg] + 1e-9f);
        }
      }
    }
  }

  lloss = block_reduce(lloss, false, red);
  if (tid == 0) partials[f + (bt << 10)] = lloss;
}

// ---------------------------------------------------------------------------
// Kernel 4: reduce 4096 block partials -> out[0] = mean over 16384 rows.
// ---------------------------------------------------------------------------
__global__ __launch_bounds__(256) void reduce_loss_kernel(
    const float* __restrict__ partials, float* __restrict__ out) {
  const int tid = threadIdx.x;
  __shared__ float red[4];
  float s = 0.f;
  for (int i = tid; i < 4096; i += 256) s += partials[i];
  s = block_reduce(s, false, red);
  if (tid == 0) out[0] = s * (1.0f / (float)NROWS);
}

// ---------------------------------------------------------------------------
extern "C" void kernel_launch(void* const* d_in, const int* in_sizes, int n_in,
                              void* d_out, int out_size, void* d_ws, size_t ws_size,
                              hipStream_t stream) {
  const float* hidden  = (const float*)d_in[0];
  const float* Wq_mlp  = (const float*)d_in[1];
  const float* bq_mlp  = (const float*)d_in[2];
  const float* Wk_mlp  = (const float*)d_in[3];
  const float* bk_mlp  = (const float*)d_in[4];
  const float* Wq_base = (const float*)d_in[5];
  const float* Wk_base = (const float*)d_in[6];
  float* out = (float*)d_out;
  ushort_t* ws = (ushort_t*)d_ws;
  float* fst = (float*)(ws + FSTAT_BASE);  // mt/ist/mp/isp/partials

  proj_kernel<<<NROWS / PR, 256, 0, stream>>>(hidden, Wq_mlp, bq_mlp, Wk_mlp,
                                              bk_mlp, Wq_base, Wk_base, ws);
  stats_kernel<<<256, 256, 0, stream>>>(ws, fst);
  scores_write_kernel<<<dim3(32, 32, B), 256, 0, stream>>>(ws, out, fst);
  reduce_loss_kernel<<<1, 256, 0, stream>>>(fst + 65536, out);
}

// Round 7
// 786.265 us; speedup vs baseline: 1.3987x; 1.3987x over previous
//
#include <hip/hip_runtime.h>
#include <hip/hip_bf16.h>
#include <math.h>

// Problem: b=4, n=4096, d=64.
// d_out (fp32 concat): [loss(1)] [pred_attn 4*4096*4096] [true_attn 4*4096*4096]
//
// ws layout (ushort/bf16 unless noted), element offsets:
//   qbh 0        qbl 1048576   kbh 2097152   kbl 3145728     (each 4*4096*64)
//   qfh 4194304  qfl 6291456   kfh 8388608   kfl 10485760    (each 4*4096*128)
//   then floats at ushort offset 12582912:
//     mt[16384] ist[16384] mp[16384] isp[16384] partials[4096]
//
// R7 changes vs R6 (1099.8 us measured, REGRESSION):
//  - REVERT nontemporal stores: R6 counters showed WRITE_SIZE 1.06 GB = 2x
//    algorithmic (partial 64B-segment nt writes bypass L2 write-coalescing
//    -> HBM RMW amplification; 2.0 TB/s effective). Plain stores let L2
//    merge the 4x64B wave segments into full lines. FETCH was only 64 MB,
//    so the "keep ws in L2" motivation for nt was moot anyway.
//  - KEEP __expf/__logf (R6's other change) -> R7 vs R5 isolates that term.

#define B 4
#define N 4096
#define D 64
#define NROWS (B * N)
#define ATTN_ELEMS ((size_t)B * N * N)
#define FSTAT_BASE 12582912  // ushort offset of float stats area

typedef __attribute__((ext_vector_type(8))) short short8;   // 8 bf16 = 4 VGPRs
typedef __attribute__((ext_vector_type(4))) float float4v;  // MFMA C/D

typedef unsigned short ushort_t;

__device__ __forceinline__ float fast_exp(float x) { return __expf(x); }
__device__ __forceinline__ float fast_log(float x) { return __logf(x); }

__device__ __forceinline__ void split_bf16(float x, ushort_t& hi, ushort_t& lo) {
  __hip_bfloat16 h = __float2bfloat16(x);
  float r = x - __bfloat162float(h);
  __hip_bfloat16 l = __float2bfloat16(r);
  hi = *(ushort_t*)&h;
  lo = *(ushort_t*)&l;
}

__device__ __forceinline__ void gload_lds16(const ushort_t* g, ushort_t* l) {
  __builtin_amdgcn_global_load_lds(
      (const __attribute__((address_space(1))) unsigned int*)g,
      (__attribute__((address_space(3))) unsigned int*)l, 16, 0, 0);
}

__device__ __forceinline__ float block_reduce(float v, bool is_max, float* red) {
#pragma unroll
  for (int o = 32; o > 0; o >>= 1) {
    float other = __shfl_down(v, o);
    v = is_max ? fmaxf(v, other) : (v + other);
  }
  int w = threadIdx.x >> 6;
  __syncthreads();
  if ((threadIdx.x & 63) == 0) red[w] = v;
  __syncthreads();
  return is_max ? fmaxf(fmaxf(red[0], red[1]), fmaxf(red[2], red[3]))
                : (red[0] + red[1] + red[2] + red[3]);
}

// ---------------------------------------------------------------------------
// Kernel 1: projections + feature maps + split-bf16 (unchanged from R2).
// ---------------------------------------------------------------------------
#define PR 32

__global__ __launch_bounds__(256, 2) void proj_kernel(
    const float* __restrict__ hidden,
    const float* __restrict__ Wq_mlp, const float* __restrict__ bq_mlp,
    const float* __restrict__ Wk_mlp, const float* __restrict__ bk_mlp,
    const float* __restrict__ Wq_base, const float* __restrict__ Wk_base,
    ushort_t* __restrict__ ws) {
  ushort_t* qbh = ws;
  ushort_t* qbl = ws + 1048576;
  ushort_t* kbh = ws + 2097152;
  ushort_t* kbl = ws + 3145728;
  ushort_t* qfh = ws + 4194304;
  ushort_t* qfl = ws + 6291456;
  ushort_t* kfh = ws + 8388608;
  ushort_t* kfl = ws + 10485760;

  __shared__ float wt[4][64 * 64];  // 64 KB: [mat][d*64 + (e ^ (d&31))]
  __shared__ float hs[PR][64];      // 8 KB

  const int tid = threadIdx.x;
  const int r0 = blockIdx.x * PR;

  {
    const float* Wm[4] = {Wq_base, Wk_base, Wq_mlp, Wk_mlp};
#pragma unroll
    for (int m = 0; m < 4; ++m)
      for (int idx = tid; idx < 4096; idx += 256) {
        const int e = idx >> 6, d = idx & 63;
        wt[m][d * 64 + (e ^ (d & 31))] = Wm[m][idx];
      }
  }
  for (int idx = tid; idx < PR * 64; idx += 256)
    hs[idx >> 6][idx & 63] = hidden[(size_t)r0 * 64 + idx];
  __syncthreads();

  const int e = tid & 63;
  const int g0 = (tid >> 6) * (PR / 4);  // 8 rows per thread

  float aqb[PR / 4], akb[PR / 4], zq[PR / 4], zk[PR / 4];
  const float bq = bq_mlp[e], bk = bk_mlp[e];
#pragma unroll
  for (int g = 0; g < PR / 4; ++g) {
    aqb[g] = 0.f; akb[g] = 0.f; zq[g] = bq; zk[g] = bk;
  }

#pragma unroll 8
  for (int d = 0; d < 64; ++d) {
    const int wi = d * 64 + (e ^ (d & 31));
    const float w0 = wt[0][wi];
    const float w1 = wt[1][wi];
    const float w2 = wt[2][wi];
    const float w3 = wt[3][wi];
#pragma unroll
    for (int g = 0; g < PR / 4; ++g) {
      const float hd = hs[g0 + g][d];
      aqb[g] += hd * w0;
      akb[g] += hd * w1;
      zq[g] += hd * w2;
      zk[g] += hd * w3;
    }
  }

#pragma unroll
  for (int g = 0; g < PR / 4; ++g) {
    const int row = r0 + g0 + g;
    const size_t rb = (size_t)row * D + e;       // base rows, stride 64
    const size_t rf = (size_t)row * 2 * D + e;   // feature rows, stride 128
    ushort_t hi, lo;
    split_bf16(aqb[g], hi, lo);        qbh[rb] = hi; qbl[rb] = lo;
    split_bf16(akb[g], hi, lo);        kbh[rb] = hi; kbl[rb] = lo;
    split_bf16(expf(zq[g]), hi, lo);   qfh[rf] = hi; qfl[rf] = lo;
    split_bf16(expf(-zq[g]), hi, lo);  qfh[rf + D] = hi; qfl[rf + D] = lo;
    split_bf16(expf(zk[g]), hi, lo);   kfh[rf] = hi; kfl[rf] = lo;
    split_bf16(expf(-zk[g]), hi, lo);  kfh[rf + D] = hi; kfl[rf + D] = lo;
  }
}

// ---------------------------------------------------------------------------
// Kernel 2: row softmax stats (MT, 1/ST, MP, 1/SP) via recompute, no score
// write. Structure unchanged from R5; expf -> __expf only.
// ---------------------------------------------------------------------------
__global__ __launch_bounds__(256) void stats_kernel(
    const ushort_t* __restrict__ ws, float* __restrict__ fst) {
  const ushort_t* qbh = ws;
  const ushort_t* qbl = ws + 1048576;
  const ushort_t* kbh = ws + 2097152;
  const ushort_t* kbl = ws + 3145728;
  const ushort_t* qfh = ws + 4194304;
  const ushort_t* qfl = ws + 6291456;
  const ushort_t* kfh = ws + 8388608;
  const ushort_t* kfl = ws + 10485760;

  float* mt_ = fst;
  float* ist_ = fst + 16384;
  float* mp_ = fst + 32768;
  float* isp_ = fst + 49152;

  __shared__ ushort_t sbh[128 * 64];    // 16 KB
  __shared__ ushort_t sbl[128 * 64];    // 16 KB
  __shared__ ushort_t sfh[128 * 128];   // 32 KB
  __shared__ ushort_t sfl[128 * 128];   // 32 KB

  const int bid0 = blockIdx.x;                     // 0..255
  const int bid = (bid0 & 7) * 32 + (bid0 >> 3);   // XCD-chunked, bijective
  const int bt = bid >> 6;                         // batch
  const int m0 = (bid & 63) * 64;                  // 64-row strip
  const int tid = threadIdx.x;
  const int w = tid >> 6;                          // wave: rows m0+w*16..+16
  const int lane = tid & 63;
  const int fr = lane & 15;
  const int quad = lane >> 4;
  const size_t rowb = (size_t)bt * N;

  // A fragments: row = fr (within wave strip), k-slice = quad*8 + kk*32
  const size_t ar = rowb + m0 + w * 16 + fr;
  short8 ath[2], atl[2], aph[4], apl[4];
#pragma unroll
  for (int kk = 0; kk < 2; ++kk) {
    ath[kk] = *(const short8*)&qbh[ar * 64 + kk * 32 + quad * 8];
    atl[kk] = *(const short8*)&qbl[ar * 64 + kk * 32 + quad * 8];
  }
#pragma unroll
  for (int kk = 0; kk < 4; ++kk) {
    aph[kk] = *(const short8*)&qfh[ar * 128 + kk * 32 + quad * 8];
    apl[kk] = *(const short8*)&qfl[ar * 128 + kk * 32 + quad * 8];
  }

  const int sr8 = lane >> 3, su8 = (lane & 7) ^ (lane >> 3);  // kb staging
  const int r4 = lane >> 4, u16 = lane & 15;                  // kf staging

  float m_t[4], s_t[4], m_p[4], s_p[4];
#pragma unroll
  for (int r = 0; r < 4; ++r) {
    m_t[r] = -INFINITY; s_t[r] = 0.f;
    m_p[r] = -INFINITY; s_p[r] = 0.f;
  }

  for (int c = 0; c < 32; ++c) {
    const int n0 = c * 128;
    __syncthreads();
    // stage kb: 16 groups of 8 rows x 64 ushort; wave w takes g = j*4+w
#pragma unroll
    for (int j = 0; j < 4; ++j) {
      const int g = j * 4 + w;
      const size_t grow = rowb + n0 + g * 8 + sr8;
      gload_lds16(kbh + grow * 64 + su8 * 8, &sbh[g * 512]);
      gload_lds16(kbl + grow * 64 + su8 * 8, &sbl[g * 512]);
    }
    // stage kf: 32 groups of 4 rows x 128 ushort
#pragma unroll
    for (int j = 0; j < 8; ++j) {
      const int g = j * 4 + w;
      const int su = u16 ^ ((g & 1) * 4 + r4);   // = u ^ (row&7)
      const size_t grow = rowb + n0 + g * 4 + r4;
      gload_lds16(kfh + grow * 128 + su * 8, &sfh[g * 512]);
      gload_lds16(kfl + grow * 128 + su * 8, &sfl[g * 512]);
    }
    __syncthreads();

    // ---- true scores: K=64 ----
    float4v acct[8];
#pragma unroll
    for (int tn = 0; tn < 8; ++tn) acct[tn] = (float4v)0.f;
#pragma unroll
    for (int tn = 0; tn < 8; ++tn) {
      const int brow = tn * 16 + fr;
#pragma unroll
      for (int kk = 0; kk < 2; ++kk) {
        const int u = ((kk * 4 + quad) ^ (fr & 7)) * 8;
        short8 bh = *(const short8*)&sbh[brow * 64 + u];
        short8 bl = *(const short8*)&sbl[brow * 64 + u];
        acct[tn] = __builtin_amdgcn_mfma_f32_16x16x32_bf16(ath[kk], bh, acct[tn], 0, 0, 0);
        acct[tn] = __builtin_amdgcn_mfma_f32_16x16x32_bf16(ath[kk], bl, acct[tn], 0, 0, 0);
        acct[tn] = __builtin_amdgcn_mfma_f32_16x16x32_bf16(atl[kk], bh, acct[tn], 0, 0, 0);
      }
    }
#pragma unroll
    for (int r = 0; r < 4; ++r) {
      float vm = m_t[r];
      float v[8];
#pragma unroll
      for (int tn = 0; tn < 8; ++tn) { v[tn] = acct[tn][r] * 0.125f; vm = fmaxf(vm, v[tn]); }
      float ss = s_t[r] * fast_exp(m_t[r] - vm);
#pragma unroll
      for (int tn = 0; tn < 8; ++tn) ss += fast_exp(v[tn] - vm);
      m_t[r] = vm; s_t[r] = ss;
    }

    // ---- pred scores: K=128 ----
    float4v accp[8];
#pragma unroll
    for (int tn = 0; tn < 8; ++tn) accp[tn] = (float4v)0.f;
#pragma unroll
    for (int tn = 0; tn < 8; ++tn) {
      const int brow = tn * 16 + fr;
#pragma unroll
      for (int kk = 0; kk < 4; ++kk) {
        const int u = ((kk * 4 + quad) ^ (fr & 7)) * 8;
        short8 bh = *(const short8*)&sfh[brow * 128 + u];
        short8 bl = *(const short8*)&sfl[brow * 128 + u];
        accp[tn] = __builtin_amdgcn_mfma_f32_16x16x32_bf16(aph[kk], bh, accp[tn], 0, 0, 0);
        accp[tn] = __builtin_amdgcn_mfma_f32_16x16x32_bf16(aph[kk], bl, accp[tn], 0, 0, 0);
        accp[tn] = __builtin_amdgcn_mfma_f32_16x16x32_bf16(apl[kk], bh, accp[tn], 0, 0, 0);
      }
    }
#pragma unroll
    for (int r = 0; r < 4; ++r) {
      float vm = m_p[r];
      float v[8];
#pragma unroll
      for (int tn = 0; tn < 8; ++tn) { v[tn] = accp[tn][r]; vm = fmaxf(vm, v[tn]); }
      float ss = s_p[r] * fast_exp(m_p[r] - vm);
#pragma unroll
      for (int tn = 0; tn < 8; ++tn) ss += fast_exp(v[tn] - vm);
      m_p[r] = vm; s_p[r] = ss;
    }
  }

  // combine across the 16 fr lanes (masks 1,2,4,8 stay within quad group)
#pragma unroll
  for (int r = 0; r < 4; ++r) {
    {
      float m = m_t[r], s = s_t[r];
#pragma unroll
      for (int o = 1; o < 16; o <<= 1) {
        float m2 = __shfl_xor(m, o);
        float s2 = __shfl_xor(s, o);
        float M = fmaxf(m, m2);
        s = s * fast_exp(m - M) + s2 * fast_exp(m2 - M);
        m = M;
      }
      if (fr == 0) {
        const size_t row = rowb + m0 + w * 16 + quad * 4 + r;
        mt_[row] = m; ist_[row] = 1.f / s;
      }
    }
    {
      float m = m_p[r], s = s_p[r];
#pragma unroll
      for (int o = 1; o < 16; o <<= 1) {
        float m2 = __shfl_xor(m, o);
        float s2 = __shfl_xor(s, o);
        float M = fmaxf(m, m2);
        s = s * fast_exp(m - M) + s2 * fast_exp(m2 - M);
        m = M;
      }
      if (fr == 0) {
        const size_t row = rowb + m0 + w * 16 + quad * 4 + r;
        mp_[row] = m; isp_[row] = 1.f / s;
      }
    }
  }
}

// ---------------------------------------------------------------------------
// Kernel 3: scores -> NORMALIZED probabilities + loss partials.
// Structure unchanged from R5; epilogue uses __expf/__logf, plain stores.
// ---------------------------------------------------------------------------
__global__ __launch_bounds__(256, 2) void scores_write_kernel(
    const ushort_t* __restrict__ ws, float* __restrict__ out,
    float* __restrict__ fst) {
  const ushort_t* qbh = ws;
  const ushort_t* qbl = ws + 1048576;
  const ushort_t* kbh = ws + 2097152;
  const ushort_t* kbl = ws + 3145728;
  const ushort_t* qfh = ws + 4194304;
  const ushort_t* qfl = ws + 6291456;
  const ushort_t* kfh = ws + 8388608;
  const ushort_t* kfl = ws + 10485760;

  const float* mt_ = fst;
  const float* ist_ = fst + 16384;
  const float* mp_ = fst + 32768;
  const float* isp_ = fst + 49152;
  float* partials = fst + 65536;

  __shared__ ushort_t sAh[128 * 64];
  __shared__ ushort_t sAl[128 * 64];
  __shared__ ushort_t sBh[128 * 64];
  __shared__ ushort_t sBl[128 * 64];
  __shared__ float red[4];

  const int bt = blockIdx.z;
  const int f = blockIdx.x + 32 * blockIdx.y;     // 0..1023, %8 tracks XCD
  const int nf = (f & 7) * 128 + (f >> 3);        // bijective chunked swizzle
  const int m0 = (nf >> 5) * 128;
  const int n0 = (nf & 31) * 128;

  const int tid = threadIdx.x;
  const int lane = tid & 63;
  const int w = tid >> 6;
  const int qr = w >> 1, qc = w & 1;     // quadrant row/col (64 each)
  const int fr = lane & 15;              // fragment row within 16
  const int quad = lane >> 4;            // 0..3

  const int srow = lane >> 3;                 // r&7 of this lane's stage row
  const int sunit = (lane & 7) ^ srow;        // pre-swizzled source unit

  const size_t rowb = (size_t)bt * N;
  float* pred = out + 1;
  float* tru  = out + 1 + ATTN_ELEMS;

  float4v tsave[4][4];   // normalized true tile, phase0 -> phase1 loss
  float lloss = 0.f;

#pragma unroll
  for (int phase = 0; phase < 2; ++phase) {
    const ushort_t* Ah = phase ? qfh : qbh;
    const ushort_t* Al = phase ? qfl : qbl;
    const ushort_t* Bh = phase ? kfh : kbh;
    const ushort_t* Bl = phase ? kfl : kbl;
    const int Krow = phase ? 128 : 64;
    const int nchunk = Krow / 64;
    const float scale = phase ? 1.0f : 0.125f;
    float* dst = phase ? pred : tru;

    float4v acc[4][4];
#pragma unroll
    for (int i = 0; i < 4; ++i)
#pragma unroll
      for (int j = 0; j < 4; ++j) acc[i][j] = (float4v)0.f;

    for (int ck = 0; ck < nchunk; ++ck) {
      const int kc = ck * 64;
      __syncthreads();  // previous chunk's fragment reads done
#pragma unroll
      for (int j = 0; j < 4; ++j) {
        const int chunk = j * 4 + w;
        const int r = chunk * 8 + srow;
        const int loff = chunk * 512;  // ushort offset of 1 KB chunk
        const size_t gA = (size_t)(rowb + m0 + r) * Krow + kc + sunit * 8;
        const size_t gB = (size_t)(rowb + n0 + r) * Krow + kc + sunit * 8;
        gload_lds16(Ah + gA, &sAh[loff]);
        gload_lds16(Al + gA, &sAl[loff]);
        gload_lds16(Bh + gB, &sBh[loff]);
        gload_lds16(Bl + gB, &sBl[loff]);
      }
      __syncthreads();  // vmcnt(0) drain emitted by compiler before barrier

#pragma unroll
      for (int kk = 0; kk < 2; ++kk) {
        short8 ah[4], al[4], bh[4], bl[4];
        const int u8 = ((kk * 4 + quad) ^ (fr & 7)) * 8;  // swizzled unit
#pragma unroll
        for (int t = 0; t < 4; ++t) {
          const int offA = (qr * 64 + t * 16 + fr) * 64 + u8;
          const int offB = (qc * 64 + t * 16 + fr) * 64 + u8;
          ah[t] = *(const short8*)&sAh[offA];
          al[t] = *(const short8*)&sAl[offA];
          bh[t] = *(const short8*)&sBh[offB];
          bl[t] = *(const short8*)&sBl[offB];
        }
#pragma unroll
        for (int tm = 0; tm < 4; ++tm)
#pragma unroll
          for (int tn = 0; tn < 4; ++tn) {
            acc[tm][tn] = __builtin_amdgcn_mfma_f32_16x16x32_bf16(
                ah[tm], bh[tn], acc[tm][tn], 0, 0, 0);
            acc[tm][tn] = __builtin_amdgcn_mfma_f32_16x16x32_bf16(
                ah[tm], bl[tn], acc[tm][tn], 0, 0, 0);
            acc[tm][tn] = __builtin_amdgcn_mfma_f32_16x16x32_bf16(
                al[tm], bh[tn], acc[tm][tn], 0, 0, 0);
          }
      }
    }

    // epilogue: normalize with precomputed row stats, write, track loss
#pragma unroll
    for (int tm = 0; tm < 4; ++tm) {
      const int rbase = m0 + qr * 64 + tm * 16 + quad * 4;
      float mrow[4], isrow[4];
#pragma unroll
      for (int reg = 0; reg < 4; ++reg) {
        const size_t gr = rowb + rbase + reg;
        mrow[reg]  = phase ? mp_[gr]  : mt_[gr];
        isrow[reg] = phase ? isp_[gr] : ist_[gr];
      }
#pragma unroll
      for (int tn = 0; tn < 4; ++tn) {
        const int c = n0 + qc * 64 + tn * 16 + fr;
        float4v v = acc[tm][tn];
        float4v pv;
#pragma unroll
        for (int reg = 0; reg < 4; ++reg)
          pv[reg] = fast_exp(v[reg] * scale - mrow[reg]) * isrow[reg];
#pragma unroll
        for (int reg = 0; reg < 4; ++reg)
          dst[(rowb + rbase + reg) * N + c] = pv[reg];
        if (phase == 0) {
          tsave[tm][tn] = pv;
        } else {
#pragma unroll
          for (int reg = 0; reg < 4; ++reg)
            lloss -= tsave[tm][tn][reg] * fast_log(pv[reg] + 1e-9f);
        }
      }
    }
  }

  lloss = block_reduce(lloss, false, red);
  if (tid == 0) partials[f + (bt << 10)] = lloss;
}

// ---------------------------------------------------------------------------
// Kernel 4: reduce 4096 block partials -> out[0] = mean over 16384 rows.
// ---------------------------------------------------------------------------
__global__ __launch_bounds__(256) void reduce_loss_kernel(
    const float* __restrict__ partials, float* __restrict__ out) {
  const int tid = threadIdx.x;
  __shared__ float red[4];
  float s = 0.f;
  for (int i = tid; i < 4096; i += 256) s += partials[i];
  s = block_reduce(s, false, red);
  if (tid == 0) out[0] = s * (1.0f / (float)NROWS);
}

// ---------------------------------------------------------------------------
extern "C" void kernel_launch(void* const* d_in, const int* in_sizes, int n_in,
                              void* d_out, int out_size, void* d_ws, size_t ws_size,
                              hipStream_t stream) {
  const float* hidden  = (const float*)d_in[0];
  const float* Wq_mlp  = (const float*)d_in[1];
  const float* bq_mlp  = (const float*)d_in[2];
  const float* Wk_mlp  = (const float*)d_in[3];
  const float* bk_mlp  = (const float*)d_in[4];
  const float* Wq_base = (const float*)d_in[5];
  const float* Wk_base = (const float*)d_in[6];
  float* out = (float*)d_out;
  ushort_t* ws = (ushort_t*)d_ws;
  float* fst = (float*)(ws + FSTAT_BASE);  // mt/ist/mp/isp/partials

  proj_kernel<<<NROWS / PR, 256, 0, stream>>>(hidden, Wq_mlp, bq_mlp, Wk_mlp,
                                              bk_mlp, Wq_base, Wk_base, ws);
  stats_kernel<<<256, 256, 0, stream>>>(ws, fst);
  scores_write_kernel<<<dim3(32, 32, B), 256, 0, stream>>>(ws, out, fst);
  reduce_loss_kernel<<<1, 256, 0, stream>>>(fst + 65536, out);
}